// Round 7
// baseline (949.804 us; speedup 1.0000x reference)
//
#include <hip/hip_runtime.h>
#include <hip/hip_bf16.h>

// RGAT pipeline for MI355X. Inputs f32, OUTPUTS f32. Scratch (~84.2 MB) lives
// in d_out's f32 adj region (144 MB), all dead before adj_kernel, which reads
// mu from out_mu (disjoint from the adj range it writes). d_ws/d_in untouched.
//
// R1: agg flash-style online-softmax, vectorized multi-edge float4 gather.
// R2: adj 512-thr 8x4 blocking, conflict-free LDS.
// R3/R4 FAILED: el3/er3 under-allocation collided with er3[0]/hx.
// R5: dedicated el3/er3; 3-phase CSR scan; batched mu/mu/logvar layers.
// R6: agg software-pipelined across relations (fast path deg<=64 all r).
// R7: adj __launch_bounds__(512, 1): R2-R6 ran at VGPR_Count=48 while the
//     k-loop needs ~80 live floats (res[32]+acc[32]+frags) -> compiler was
//     shuffling accumulators through AGPRs/scratch; VALU-issue time 75 us vs
//     29 us pure-FMA floor. Releasing the VGPR cap removes the move traffic.

static constexpr int N_  = 20000;
static constexpr int R_  = 3;
static constexpr int E_  = 200000;
static constexpr int NB1 = 6000;   // N1 == N2 == 6000

__device__ __forceinline__ float sigmoidf_(float x) {
  return 1.0f / (1.0f + __expf(-x));
}

// ---------------- CSR build ----------------
__global__ void hist_kernel(const int* __restrict__ dst, int* __restrict__ counts) {
  int i = blockIdx.x * blockDim.x + threadIdx.x;
  if (i >= R_ * E_) return;
  int r = i / E_;
  atomicAdd(&counts[r * N_ + dst[i]], 1);
}

static constexpr int SCAN_CH = 1024;
static constexpr int NCH = (N_ + SCAN_CH - 1) / SCAN_CH;  // 20

// Phase A: per-1024-chunk local exclusive scan + chunk totals.
__global__ __launch_bounds__(1024) void scan_partial_kernel(
    const int* __restrict__ counts, int* __restrict__ ptr, int* __restrict__ csums) {
  const int r = blockIdx.y, c = blockIdx.x, tid = threadIdx.x;
  __shared__ int buf[SCAN_CH];
  const int i = c * SCAN_CH + tid;
  const int v = (i < N_) ? counts[r * N_ + i] : 0;
  buf[tid] = v;
  __syncthreads();
  for (int off = 1; off < SCAN_CH; off <<= 1) {
    int t = (tid >= off) ? buf[tid - off] : 0;
    __syncthreads();
    buf[tid] += t;
    __syncthreads();
  }
  if (i < N_) ptr[r * (N_ + 1) + i] = buf[tid] - v;  // local exclusive
  if (tid == SCAN_CH - 1) csums[r * NCH + c] = buf[tid];
}

// Phase B: tiny serial scan of chunk totals (R_ threads, 20 entries each).
__global__ void scan_sums_kernel(int* __restrict__ csums, int* __restrict__ ptr) {
  int r = threadIdx.x;
  if (r < R_) {
    int acc = 0;
    for (int c = 0; c < NCH; ++c) {
      int t = csums[r * NCH + c];
      csums[r * NCH + c] = acc;
      acc += t;
    }
    ptr[r * (N_ + 1) + N_] = acc;
  }
}

// Phase C: add chunk bases.
__global__ __launch_bounds__(1024) void scan_add_kernel(
    const int* __restrict__ csums, int* __restrict__ ptr) {
  const int r = blockIdx.y, c = blockIdx.x, tid = threadIdx.x;
  const int i = c * SCAN_CH + tid;
  if (i < N_) ptr[r * (N_ + 1) + i] += csums[r * NCH + c];
}

__global__ void scatter_kernel(const int* __restrict__ src, const int* __restrict__ dst,
                               const int* __restrict__ ptr, int* __restrict__ fill,
                               int* __restrict__ csrc) {
  int i = blockIdx.x * blockDim.x + threadIdx.x;
  if (i >= R_ * E_) return;
  int r = i / E_;
  int d = dst[i];
  int pos = ptr[r * (N_ + 1) + d] + atomicAdd(&fill[r * N_ + d], 1);
  csrc[r * E_ + pos] = src[i];
}

// ---------------- GEMM + fused attention-logit epilogue ----------------
// h[r][n][HF] = A[n][:] @ W[r][:][:] (f32); el/er[r][n][hh] = sum_f h*al/ar.
// 256 threads = 16x16, tile 64 nodes x 64 cols, 4x4 register blocking.
template <int DIN, int HF, int H, int F>
__device__ __forceinline__ void gemm_el_dev(
    const int r, const float* __restrict__ A, const float* __restrict__ W,
    const float* __restrict__ al, const float* __restrict__ ar,
    float* __restrict__ h, float* __restrict__ el, float* __restrict__ er) {
  __shared__ float sAT[64][68];  // [k][node]
  __shared__ float sW[64][68];   // [k][col]
  const int nb  = blockIdx.x * 64;
  const int cg  = blockIdx.y;    // 64-col group
  const int tid = threadIdx.x;
  const int ty  = tid >> 4, tx = tid & 15;

  float acc[4][4];
#pragma unroll
  for (int i = 0; i < 4; ++i)
#pragma unroll
    for (int j = 0; j < 4; ++j) acc[i][j] = 0.f;

  for (int k0 = 0; k0 < DIN; k0 += 64) {
    for (int idx = tid; idx < 4096; idx += 256) {
      int nl = idx >> 6, kk = idx & 63;
      int n = nb + nl;
      sAT[kk][nl] = (n < N_) ? A[(size_t)n * DIN + k0 + kk] : 0.f;
    }
    for (int idx = tid; idx < 4096; idx += 256) {
      int kk = idx >> 6, cl = idx & 63;
      sW[kk][cl] = W[((size_t)r * DIN + k0 + kk) * HF + cg * 64 + cl];
    }
    __syncthreads();
#pragma unroll 8
    for (int kk = 0; kk < 64; ++kk) {
      const float4 a4 = *(const float4*)&sAT[kk][ty * 4];
      const float4 w4 = *(const float4*)&sW[kk][tx * 4];
      const float a[4] = {a4.x, a4.y, a4.z, a4.w};
      const float w[4] = {w4.x, w4.y, w4.z, w4.w};
#pragma unroll
      for (int i = 0; i < 4; ++i)
#pragma unroll
        for (int j = 0; j < 4; ++j) acc[i][j] = fmaf(a[i], w[j], acc[i][j]);
    }
    __syncthreads();
  }

  // store h (float4 per row)
  const int c0 = cg * 64 + tx * 4;
#pragma unroll
  for (int i = 0; i < 4; ++i) {
    int n = nb + ty * 4 + i;
    if (n < N_) {
      float4 v; v.x = acc[i][0]; v.y = acc[i][1]; v.z = acc[i][2]; v.w = acc[i][3];
      *(float4*)&h[((size_t)r * N_ + n) * HF + c0] = v;
    }
  }

  // fused el/er: reduce over f within head via shuffles (group width G = F/4)
  const int hh = c0 / F;
  const int f0 = c0 % F;
  float al4[4], ar4[4];
#pragma unroll
  for (int j = 0; j < 4; ++j) {
    al4[j] = al[((size_t)r * H + hh) * F + f0 + j];
    ar4[j] = ar[((size_t)r * H + hh) * F + f0 + j];
  }
  float elp[4], erp[4];
#pragma unroll
  for (int i = 0; i < 4; ++i) {
    elp[i] = acc[i][0] * al4[0] + acc[i][1] * al4[1] + acc[i][2] * al4[2] + acc[i][3] * al4[3];
    erp[i] = acc[i][0] * ar4[0] + acc[i][1] * ar4[1] + acc[i][2] * ar4[2] + acc[i][3] * ar4[3];
  }
  constexpr int G = F / 4;  // tx-threads per head: 16 (F=64) or 8 (F=32)
#pragma unroll
  for (int off = G / 2; off >= 1; off >>= 1) {
#pragma unroll
    for (int i = 0; i < 4; ++i) {
      elp[i] += __shfl_down(elp[i], off, G);
      erp[i] += __shfl_down(erp[i], off, G);
    }
  }
  if ((tx & (G - 1)) == 0) {
#pragma unroll
    for (int i = 0; i < 4; ++i) {
      int n = nb + ty * 4 + i;
      if (n < N_) {
        el[((size_t)r * N_ + n) * H + hh] = elp[i];
        er[((size_t)r * N_ + n) * H + hh] = erp[i];
      }
    }
  }
}

template <int DIN, int HF, int H, int F>
__global__ __launch_bounds__(256) void gemm_el_kernel(
    const float* __restrict__ A, const float* __restrict__ W,
    const float* __restrict__ al, const float* __restrict__ ar,
    float* __restrict__ h, float* __restrict__ el, float* __restrict__ er) {
  gemm_el_dev<DIN, HF, H, F>(blockIdx.z, A, W, al, ar, h, el, er);
}

// Batched variant: 3 instances (mu s0, mu s1, logvar), grid.z = 3*R_.
struct GemmB3 {
  const float* A[3]; const float* W[3]; const float* al[3]; const float* ar[3];
  float* h[3]; float* el[3]; float* er[3];
};
template <int DIN, int HF, int H, int F>
__global__ __launch_bounds__(256) void gemm_el_b3_kernel(GemmB3 a) {
  const int inst = blockIdx.z / R_;
  const int r    = blockIdx.z % R_;
  gemm_el_dev<DIN, HF, H, F>(r, a.A[inst], a.W[inst], a.al[inst], a.ar[inst],
                             a.h[inst], a.el[inst], a.er[inst]);
}

// ---------------- Per-destination edge softmax + aggregation ----------------
// One block per node; wave = head. Fast path (deg<=64 for all relations,
// which always holds at avg degree 10): all three relations' ptr/er/sp/el
// loads hoisted and issued together, butterflies interleaved 3-wide,
// gathers interleaved (raccv[3]). FP op sequence per relation and the
// cross-relation accumulation order are identical to the R5-verified code;
// deg==0 relations contribute exactly +0.0. Slow path = R5 loop verbatim.
template <int H, int F, bool RELU>
__device__ __forceinline__ void agg_dev(
    const int n, const float* __restrict__ h, const float* __restrict__ el,
    const float* __restrict__ er, const int* __restrict__ ptr,
    const int* __restrict__ srcs, const float* __restrict__ base,
    float* __restrict__ outf) {
  constexpr int VL  = F / 4;    // lanes per edge-row (float4 granules): 16 or 8
  constexpr int EPG = 64 / VL;  // edges per wave-iteration: 4 or 8
  const int wave = threadIdx.x >> 6;   // = head
  const int lane = threadIdx.x & 63;
  const int eg   = lane / VL;          // edge slot within iteration
  const int fl   = lane % VL;          // float4 index within row

  float4 tot = {0.f, 0.f, 0.f, 0.f};

  // hoisted ptr loads (independent across relations)
  int p0v[R_], degv[R_];
#pragma unroll
  for (int r = 0; r < R_; ++r) {
    p0v[r]  = ptr[r * (N_ + 1) + n];
    degv[r] = ptr[r * (N_ + 1) + n + 1] - p0v[r];
  }

  bool fast = true;
#pragma unroll
  for (int r = 0; r < R_; ++r) fast &= (degv[r] <= 64);

  if (__builtin_expect(fast, 1)) {
    // ---- fast path: single chunk per relation, fully pipelined ----
    float ervv[R_];
#pragma unroll
    for (int r = 0; r < R_; ++r)
      ervv[r] = er[((size_t)r * N_ + n) * H + wave];

    int sv[R_];
#pragma unroll
    for (int r = 0; r < R_; ++r)
      sv[r] = (lane < degv[r]) ? srcs[(size_t)r * E_ + p0v[r] + lane] : 0;

    float ev[R_];
#pragma unroll
    for (int r = 0; r < R_; ++r) {
      float e = -3.0e38f;
      if (lane < degv[r]) {
        e = el[((size_t)r * N_ + sv[r]) * H + wave] + ervv[r];
        e = (e > 0.f) ? e : 0.2f * e;
      }
      ev[r] = e;
    }

    // interleaved max butterflies (3 independent chains)
    float mv[R_];
#pragma unroll
    for (int r = 0; r < R_; ++r) mv[r] = ev[r];
#pragma unroll
    for (int off = 32; off >= 1; off >>= 1) {
#pragma unroll
      for (int r = 0; r < R_; ++r)
        mv[r] = fmaxf(mv[r], __shfl_xor(mv[r], off, 64));
    }

    // weights (exp(e - m); padded lanes -> exactly 0; deg==0 -> all 1 but
    // racc stays 0 so the relation contributes +0.0)
    float wv[R_];
#pragma unroll
    for (int r = 0; r < R_; ++r) wv[r] = __expf(ev[r] - mv[r]);

    // interleaved wsum butterflies
    float wsv[R_];
#pragma unroll
    for (int r = 0; r < R_; ++r) wsv[r] = wv[r];
#pragma unroll
    for (int off = 32; off >= 1; off >>= 1) {
#pragma unroll
      for (int r = 0; r < R_; ++r)
        wsv[r] += __shfl_xor(wsv[r], off, 64);
    }

    // interleaved gathers
    float4 raccv[R_];
#pragma unroll
    for (int r = 0; r < R_; ++r) raccv[r] = {0.f, 0.f, 0.f, 0.f};
    int kmaxv[R_];
#pragma unroll
    for (int r = 0; r < R_; ++r) kmaxv[r] = (degv[r] + EPG - 1) / EPG;
    int kmax_all = 0;
#pragma unroll
    for (int r = 0; r < R_; ++r) kmax_all = max(kmax_all, kmaxv[r]);

    for (int k = 0; k < kmax_all; ++k) {
      const int i2 = eg + k * EPG;  // < 64 always
#pragma unroll
      for (int r = 0; r < R_; ++r) {
        if (k < kmaxv[r]) {
          const int   s2 = __shfl(sv[r], i2, 64);
          const float w2 = __shfl(wv[r], i2, 64);
          const float4 hv =
              *(const float4*)&h[((size_t)r * N_ + s2) * (H * F) + wave * F + fl * 4];
          raccv[r].x = fmaf(w2, hv.x, raccv[r].x);
          raccv[r].y = fmaf(w2, hv.y, raccv[r].y);
          raccv[r].z = fmaf(w2, hv.z, raccv[r].z);
          raccv[r].w = fmaf(w2, hv.w, raccv[r].w);
        }
      }
    }

    // accumulate in relation order (identical to serial version)
#pragma unroll
    for (int r = 0; r < R_; ++r) {
      const float inv = 1.0f / (wsv[r] + 1e-16f);
      tot.x = fmaf(raccv[r].x, inv, tot.x);
      tot.y = fmaf(raccv[r].y, inv, tot.y);
      tot.z = fmaf(raccv[r].z, inv, tot.z);
      tot.w = fmaf(raccv[r].w, inv, tot.w);
    }
  } else {
    // ---- slow path: R5-verified chunked online softmax, verbatim ----
    for (int r = 0; r < R_; ++r) {
      const int p0  = p0v[r];
      const int deg = degv[r];
      if (deg == 0) continue;
      const int* sp = srcs + (size_t)r * E_ + p0;
      const float erv = er[((size_t)r * N_ + n) * H + wave];

      float m = -3.0e38f, dsum = 0.f;
      float4 racc = {0.f, 0.f, 0.f, 0.f};

      for (int b0 = 0; b0 < deg; b0 += 64) {
        const int cnt = min(64, deg - b0);
        int   s = 0;
        float e = -3.0e38f;
        if (lane < cnt) {
          s = sp[b0 + lane];
          e = el[((size_t)r * N_ + s) * H + wave] + erv;
          e = (e > 0.f) ? e : 0.2f * e;
        }
        float mloc = e;
#pragma unroll
        for (int off = 32; off >= 1; off >>= 1)
          mloc = fmaxf(mloc, __shfl_xor(mloc, off, 64));
        const float mnew  = fmaxf(m, mloc);
        const float scale = __expf(m - mnew);
        const float w = __expf(e - mnew);
        float wsum = w;
#pragma unroll
        for (int off = 32; off >= 1; off >>= 1)
          wsum += __shfl_xor(wsum, off, 64);
        dsum = fmaf(dsum, scale, wsum);
        racc.x *= scale; racc.y *= scale; racc.z *= scale; racc.w *= scale;
        m = mnew;

        const int kmax = (cnt + EPG - 1) / EPG;
        for (int k = 0; k < kmax; ++k) {
          const int i2 = eg + k * EPG;
          const int   s2 = __shfl(s, i2, 64);
          const float w2 = __shfl(w, i2, 64);
          const float4 hv =
              *(const float4*)&h[((size_t)r * N_ + s2) * (H * F) + wave * F + fl * 4];
          racc.x = fmaf(w2, hv.x, racc.x);
          racc.y = fmaf(w2, hv.y, racc.y);
          racc.z = fmaf(w2, hv.z, racc.z);
          racc.w = fmaf(w2, hv.w, racc.w);
        }
      }
      const float inv = 1.0f / (dsum + 1e-16f);
      tot.x = fmaf(racc.x, inv, tot.x);
      tot.y = fmaf(racc.y, inv, tot.y);
      tot.z = fmaf(racc.z, inv, tot.z);
      tot.w = fmaf(racc.w, inv, tot.w);
    }
  }

  // reduce across edge-groups (xor butterfly over offsets VL..32)
#pragma unroll
  for (int off = VL; off < 64; off <<= 1) {
    tot.x += __shfl_xor(tot.x, off, 64);
    tot.y += __shfl_xor(tot.y, off, 64);
    tot.z += __shfl_xor(tot.z, off, 64);
    tot.w += __shfl_xor(tot.w, off, 64);
  }

  __shared__ float4 sh4[H][VL];
  if (eg == 0) sh4[wave][fl] = tot;
  __syncthreads();
  if (threadIdx.x < VL) {
    float4 v = sh4[0][threadIdx.x];
#pragma unroll
    for (int hh = 1; hh < H; ++hh) {
      float4 u = sh4[hh][threadIdx.x];
      v.x += u.x; v.y += u.y; v.z += u.z; v.w += u.w;
    }
    const float sc = 1.0f / H;
    v.x *= sc; v.y *= sc; v.z *= sc; v.w *= sc;
    if (RELU) {
      v.x = fmaxf(v.x, 0.f); v.y = fmaxf(v.y, 0.f);
      v.z = fmaxf(v.z, 0.f); v.w = fmaxf(v.w, 0.f);
    }
    if (base) {
      float4 bv = *(const float4*)&base[(size_t)n * F + threadIdx.x * 4];
      v.x += bv.x; v.y += bv.y; v.z += bv.z; v.w += bv.w;
    }
    *(float4*)&outf[(size_t)n * F + threadIdx.x * 4] = v;
  }
}

template <int H, int F, bool RELU>
__global__ __launch_bounds__(256, 8) void agg_kernel(
    const float* __restrict__ h, const float* __restrict__ el, const float* __restrict__ er,
    const int* __restrict__ ptr, const int* __restrict__ srcs,
    const float* __restrict__ base, float* __restrict__ outf) {
  agg_dev<H, F, RELU>(blockIdx.x, h, el, er, ptr, srcs, base, outf);
}

// Batched agg: 3 instances (mu s0, mu s1, logvar), grid = (N, 3).
struct AggB3 {
  const float* h[3]; const float* el[3]; const float* er[3]; float* out[3];
};
__global__ __launch_bounds__(128, 8) void agg_b3_kernel(
    AggB3 a, const int* __restrict__ ptr, const int* __restrict__ srcs) {
  const int inst = blockIdx.y;
  agg_dev<2, 32, false>(blockIdx.x, a.h[inst], a.el[inst], a.er[inst],
                        ptr, srcs, nullptr, a.out[inst]);
}

// ---------------- adj = mean_s sigmoid(z1[s] @ z2[s]^T) ----------------
// 512 threads, tile 128x128, 8 rows x 4 cols per thread. Conflict-free LDS
// staging (transposed scalar writes) and contiguous float4 fragment reads.
// __launch_bounds__(512, 1): the k-loop holds ~80 live floats/thread
// (res[32]+acc[32]+frags); the default VGPR heuristic gave 48 VGPRs and the
// compiler shuffled accumulators through AGPRs (2.2x VALU inflation, R6 PMC).
__global__ __launch_bounds__(512, 1) void adj_kernel(const float* __restrict__ mu,
                                                     float* __restrict__ out) {
  __shared__ float sA[32][128];  // [d][i_local]
  __shared__ float sB[32][128];  // [d][j_local]
  const int jb = blockIdx.x * 128;
  const int ib = blockIdx.y * 128;
  const int tid = threadIdx.x;
  const int ty = tid >> 5;   // 0..15: row group (quad-split: ty*4 and 64+ty*4)
  const int tx = tid & 31;   // 0..31: col quad (tx*4)

  float res[8][4];
#pragma unroll
  for (int i = 0; i < 8; ++i)
#pragma unroll
    for (int j = 0; j < 4; ++j) res[i][j] = 0.f;

  for (int s = 0; s < 2; ++s) {
    __syncthreads();
#pragma unroll
    for (int it = 0; it < 2; ++it) {
      int idx = tid + it * 512;
      int dg = idx >> 7, row = idx & 127;   // dg: 0..7 (float4 group of d)
      int gi = ib + row;
      int gj = jb + row;
      float4 va = {0.f, 0.f, 0.f, 0.f}, vb = {0.f, 0.f, 0.f, 0.f};
      if (gi < NB1) va = *(const float4*)&mu[((size_t)s * N_ + gi) * 32 + dg * 4];
      if (gj < NB1) vb = *(const float4*)&mu[((size_t)s * N_ + NB1 + gj) * 32 + dg * 4];
      sA[dg * 4 + 0][row] = va.x; sA[dg * 4 + 1][row] = va.y;
      sA[dg * 4 + 2][row] = va.z; sA[dg * 4 + 3][row] = va.w;
      sB[dg * 4 + 0][row] = vb.x; sB[dg * 4 + 1][row] = vb.y;
      sB[dg * 4 + 2][row] = vb.z; sB[dg * 4 + 3][row] = vb.w;
    }
    __syncthreads();

    float acc[8][4];
#pragma unroll
    for (int i = 0; i < 8; ++i)
#pragma unroll
      for (int j = 0; j < 4; ++j) acc[i][j] = 0.f;
#pragma unroll 8
    for (int k = 0; k < 32; ++k) {
      float a[8], b[4];
      *(float4*)&a[0] = *(const float4*)&sA[k][ty * 4];
      *(float4*)&a[4] = *(const float4*)&sA[k][64 + ty * 4];
      *(float4*)&b[0] = *(const float4*)&sB[k][tx * 4];
#pragma unroll
      for (int i = 0; i < 8; ++i)
#pragma unroll
        for (int j = 0; j < 4; ++j) acc[i][j] = fmaf(a[i], b[j], acc[i][j]);
    }
#pragma unroll
    for (int i = 0; i < 8; ++i)
#pragma unroll
      for (int j = 0; j < 4; ++j) res[i][j] += sigmoidf_(acc[i][j]);
  }

  const bool fullc = (jb + 128) <= NB1;
#pragma unroll
  for (int i = 0; i < 8; ++i) {
    int row = ib + ((i < 4) ? (ty * 4 + i) : (64 + ty * 4 + (i - 4)));
    if (row < NB1) {
      int col = jb + tx * 4;
      if (fullc) {
        float4 p;
        p.x = 0.5f * res[i][0]; p.y = 0.5f * res[i][1];
        p.z = 0.5f * res[i][2]; p.w = 0.5f * res[i][3];
        *(float4*)&out[(size_t)row * NB1 + col] = p;
      } else {
#pragma unroll
        for (int j = 0; j < 4; ++j) {
          if (col + j < NB1) out[(size_t)row * NB1 + col + j] = 0.5f * res[i][j];
        }
      }
    }
  }
}

__global__ void rk2_kernel(const float* __restrict__ rk_lgt, float* __restrict__ out) {
  int i = threadIdx.x;
  if (i < 32) out[i] = sigmoidf_(rk_lgt[i]);
}

// ---------------- host ----------------
static inline size_t align256(size_t x) { return (x + 255) & ~(size_t)255; }

extern "C" void kernel_launch(void* const* d_in, const int* in_sizes, int n_in,
                              void* d_out, int out_size, void* d_ws, size_t ws_size,
                              hipStream_t stream) {
  (void)in_sizes; (void)n_in; (void)out_size; (void)d_ws; (void)ws_size;
  const float* x      = (const float*)d_in[0];
  const float* noise  = (const float*)d_in[1];
  const float* W1     = (const float*)d_in[2];
  const float* al1    = (const float*)d_in[3];
  const float* ar1    = (const float*)d_in[4];
  const float* We     = (const float*)d_in[5];
  const float* ale    = (const float*)d_in[6];
  const float* are    = (const float*)d_in[7];
  const float* W2     = (const float*)d_in[8];
  const float* al2    = (const float*)d_in[9];
  const float* ar2    = (const float*)d_in[10];
  const float* W3     = (const float*)d_in[11];
  const float* al3    = (const float*)d_in[12];
  const float* ar3    = (const float*)d_in[13];
  const float* rk_lgt = (const float*)d_in[14];
  const int*   src    = (const int*)d_in[15];
  const int*   dst    = (const int*)d_in[16];

  float* out_adj    = (float*)d_out;                       // (1,6000,6000)
  float* out_mu     = out_adj + (size_t)NB1 * NB1;         // (2,20000,32) @ 36,000,000
  float* out_logvar = out_mu + (size_t)2 * N_ * 32;        // (20000,32)   @ 37,280,000
  float* out_rk2    = out_logvar + (size_t)N_ * 32;        // (1,32)       @ 37,920,000

  // Scratch in the f32 adj region (144 MB; we use ~84.2 MB), dead before adj.
  char* sc = (char*)d_out;
  size_t off = 0;
  int*   ptr     = (int*)(sc + off);   off += align256((size_t)R_ * (N_ + 1) * 4);      //   240 KB
  int*   csums   = (int*)(sc + off);   off += align256((size_t)R_ * NCH * 4);           //     tiny
  int*   csr_src = (int*)(sc + off);   off += align256((size_t)R_ * E_ * 4);            //  2.40 MB
  float* el      = (float*)(sc + off); off += align256((size_t)R_ * N_ * 4 * 4);        //  0.96 MB
  float* er      = (float*)(sc + off); off += align256((size_t)R_ * N_ * 4 * 4);        //  0.96 MB
  float* el3     = (float*)(sc + off); off += align256((size_t)3 * R_ * N_ * 2 * 4);    //  1.44 MB
  float* er3     = (float*)(sc + off); off += align256((size_t)3 * R_ * N_ * 2 * 4);    //  1.44 MB
  float* hx      = (float*)(sc + off); off += align256((size_t)N_ * 64 * 4);            //  5.12 MB
  float* h1      = (float*)(sc + off); off += align256((size_t)2 * N_ * 64 * 4);        // 10.24 MB
  float* h       = (float*)(sc + off); off += align256((size_t)R_ * N_ * 256 * 4);      // 61.44 MB
  // total ~84.2 MB < 144 MB (f32 adj region)
  // counts/fill alias the h region (dead after CSR build; h written later)
  int* counts = (int*)(void*)h;
  int* fill   = (int*)(void*)((char*)(void*)h + align256((size_t)R_ * N_ * 4));
  // hM3 (3 x R x N x 64 f32 = 46.08 MB) aliases h (61.44 MB; h dead after
  // the last layer-1 agg). el3/er3 are DEDICATED (1.44 MB each; the R3/R4
  // bug was aliasing them onto the 0.96 MB el/er regions).
  float* hM3 = h;

  // ---- CSR (dst shared by all 6 rgat calls) ----
  hipMemsetAsync(counts, 0, (size_t)R_ * N_ * 4, stream);
  hipMemsetAsync(fill, 0, (size_t)R_ * N_ * 4, stream);
  int eblocks = (R_ * E_ + 255) / 256;
  hist_kernel<<<eblocks, 256, 0, stream>>>(dst, counts);
  scan_partial_kernel<<<dim3(NCH, R_), SCAN_CH, 0, stream>>>(counts, ptr, csums);
  scan_sums_kernel<<<1, 64, 0, stream>>>(csums, ptr);
  scan_add_kernel<<<dim3(NCH, R_), SCAN_CH, 0, stream>>>(csums, ptr);
  scatter_kernel<<<eblocks, 256, 0, stream>>>(src, dst, ptr, fill, csr_src);

  const dim3 g256((N_ + 63) / 64, 4, R_);

  // hiddenx = rgat(x, W1, al1, ar1, relu) -> hx (f32)
  gemm_el_kernel<128, 256, 4, 64><<<g256, 256, 0, stream>>>(x, W1, al1, ar1, h, el, er);
  agg_kernel<4, 64, true><<<N_, 256, 0, stream>>>(h, el, er, ptr, csr_src, nullptr, hx);

  // hidden1[s] = hiddenx + rgat(noise[s], We, ale, are, relu) -> h1 (f32)
  for (int s = 0; s < 2; ++s) {
    gemm_el_kernel<64, 256, 4, 64><<<g256, 256, 0, stream>>>(
        noise + (size_t)s * N_ * 64, We, ale, are, h, el, er);
    agg_kernel<4, 64, true><<<N_, 256, 0, stream>>>(
        h, el, er, ptr, csr_src, hx, h1 + (size_t)s * N_ * 64);
  }

  // Batched mu[s] (s=0,1) + logvar layers: one gemm dispatch, one agg dispatch.
  GemmB3 ga;
  AggB3  aa;
  const float* As[3]  = {h1, h1 + (size_t)N_ * 64, hx};
  const float* Ws[3]  = {W2, W2, W3};
  const float* als[3] = {al2, al2, al3};
  const float* ars[3] = {ar2, ar2, ar3};
  float* outs[3] = {out_mu, out_mu + (size_t)N_ * 32, out_logvar};
  for (int i = 0; i < 3; ++i) {
    ga.A[i]  = As[i];  ga.W[i]  = Ws[i]; ga.al[i] = als[i]; ga.ar[i] = ars[i];
    ga.h[i]  = hM3 + (size_t)i * R_ * N_ * 64;
    ga.el[i] = el3 + (size_t)i * R_ * N_ * 2;
    ga.er[i] = er3 + (size_t)i * R_ * N_ * 2;
    aa.h[i]  = ga.h[i];
    aa.el[i] = ga.el[i];
    aa.er[i] = ga.er[i];
    aa.out[i] = outs[i];
  }
  gemm_el_b3_kernel<64, 64, 2, 32><<<dim3((N_ + 63) / 64, 1, 3 * R_), 256, 0, stream>>>(ga);
  agg_b3_kernel<<<dim3(N_, 3), 128, 0, stream>>>(aa, ptr, csr_src);

  rk2_kernel<<<1, 32, 0, stream>>>(rk_lgt, out_rk2);

  // adj: reads out_mu (disjoint range), overwrites the adj-region scratch.
  adj_kernel<<<dim3((NB1 + 127) / 128, (NB1 + 127) / 128), 512, 0, stream>>>(out_mu, out_adj);
}

// Round 9
// 946.176 us; speedup vs baseline: 1.0038x; 1.0038x over previous
//
#include <hip/hip_runtime.h>
#include <hip/hip_bf16.h>

// RGAT pipeline for MI355X. Inputs f32, OUTPUTS f32. Scratch (~84.2 MB) lives
// in d_out's f32 adj region (144 MB), all dead before adj_kernel, which reads
// mu from out_mu (disjoint from the adj range it writes). d_ws/d_in untouched.
//
// R1: agg flash-style online-softmax, vectorized multi-edge float4 gather.
// R2: adj 512-thr 8x4 blocking, conflict-free LDS.
// R3/R4 FAILED: el3/er3 under-allocation collided with er3[0]/hx.
// R5: dedicated el3/er3; 3-phase CSR scan; batched mu/mu/logvar layers.
// R6: agg software-pipelined across relations (fast path deg<=64 all r).
// R7 NEUTRAL: launch_bounds(512,1) didn't move VGPR_Count (48) -> compiler
//     keeps res[] in AGPRs by choice (unified file), no per-FMA spill. Real
//     co-bottleneck: DS issue pipe -- 8x4 issues 3 ds_read_b128 per 32 FMAs
//     (288 cy DS vs 128 cy VALU per CU per k-step at 12cy/DS-instr).
// R8 (resubmit; prior round was an infra failure, kernel never ran):
//     adj 256-thr 8x8 blocking (4 DS / 64 FMA: DS instrs per FMA halved).
//     BOTH row and col quads split (ty*4 / 64+ty*4, tx*4 / 64+tx*4) so all
//     fragment reads are contiguous-float4 broadcast patterns -- avoids R1's
//     stride-8 (tx*8) 4-way bank conflict. Per-element FMA order unchanged
//     -> bit-identical output.

static constexpr int N_  = 20000;
static constexpr int R_  = 3;
static constexpr int E_  = 200000;
static constexpr int NB1 = 6000;   // N1 == N2 == 6000

__device__ __forceinline__ float sigmoidf_(float x) {
  return 1.0f / (1.0f + __expf(-x));
}

// ---------------- CSR build ----------------
__global__ void hist_kernel(const int* __restrict__ dst, int* __restrict__ counts) {
  int i = blockIdx.x * blockDim.x + threadIdx.x;
  if (i >= R_ * E_) return;
  int r = i / E_;
  atomicAdd(&counts[r * N_ + dst[i]], 1);
}

static constexpr int SCAN_CH = 1024;
static constexpr int NCH = (N_ + SCAN_CH - 1) / SCAN_CH;  // 20

// Phase A: per-1024-chunk local exclusive scan + chunk totals.
__global__ __launch_bounds__(1024) void scan_partial_kernel(
    const int* __restrict__ counts, int* __restrict__ ptr, int* __restrict__ csums) {
  const int r = blockIdx.y, c = blockIdx.x, tid = threadIdx.x;
  __shared__ int buf[SCAN_CH];
  const int i = c * SCAN_CH + tid;
  const int v = (i < N_) ? counts[r * N_ + i] : 0;
  buf[tid] = v;
  __syncthreads();
  for (int off = 1; off < SCAN_CH; off <<= 1) {
    int t = (tid >= off) ? buf[tid - off] : 0;
    __syncthreads();
    buf[tid] += t;
    __syncthreads();
  }
  if (i < N_) ptr[r * (N_ + 1) + i] = buf[tid] - v;  // local exclusive
  if (tid == SCAN_CH - 1) csums[r * NCH + c] = buf[tid];
}

// Phase B: tiny serial scan of chunk totals (R_ threads, 20 entries each).
__global__ void scan_sums_kernel(int* __restrict__ csums, int* __restrict__ ptr) {
  int r = threadIdx.x;
  if (r < R_) {
    int acc = 0;
    for (int c = 0; c < NCH; ++c) {
      int t = csums[r * NCH + c];
      csums[r * NCH + c] = acc;
      acc += t;
    }
    ptr[r * (N_ + 1) + N_] = acc;
  }
}

// Phase C: add chunk bases.
__global__ __launch_bounds__(1024) void scan_add_kernel(
    const int* __restrict__ csums, int* __restrict__ ptr) {
  const int r = blockIdx.y, c = blockIdx.x, tid = threadIdx.x;
  const int i = c * SCAN_CH + tid;
  if (i < N_) ptr[r * (N_ + 1) + i] += csums[r * NCH + c];
}

__global__ void scatter_kernel(const int* __restrict__ src, const int* __restrict__ dst,
                               const int* __restrict__ ptr, int* __restrict__ fill,
                               int* __restrict__ csrc) {
  int i = blockIdx.x * blockDim.x + threadIdx.x;
  if (i >= R_ * E_) return;
  int r = i / E_;
  int d = dst[i];
  int pos = ptr[r * (N_ + 1) + d] + atomicAdd(&fill[r * N_ + d], 1);
  csrc[r * E_ + pos] = src[i];
}

// ---------------- GEMM + fused attention-logit epilogue ----------------
// h[r][n][HF] = A[n][:] @ W[r][:][:] (f32); el/er[r][n][hh] = sum_f h*al/ar.
// 256 threads = 16x16, tile 64 nodes x 64 cols, 4x4 register blocking.
template <int DIN, int HF, int H, int F>
__device__ __forceinline__ void gemm_el_dev(
    const int r, const float* __restrict__ A, const float* __restrict__ W,
    const float* __restrict__ al, const float* __restrict__ ar,
    float* __restrict__ h, float* __restrict__ el, float* __restrict__ er) {
  __shared__ float sAT[64][68];  // [k][node]
  __shared__ float sW[64][68];   // [k][col]
  const int nb  = blockIdx.x * 64;
  const int cg  = blockIdx.y;    // 64-col group
  const int tid = threadIdx.x;
  const int ty  = tid >> 4, tx = tid & 15;

  float acc[4][4];
#pragma unroll
  for (int i = 0; i < 4; ++i)
#pragma unroll
    for (int j = 0; j < 4; ++j) acc[i][j] = 0.f;

  for (int k0 = 0; k0 < DIN; k0 += 64) {
    for (int idx = tid; idx < 4096; idx += 256) {
      int nl = idx >> 6, kk = idx & 63;
      int n = nb + nl;
      sAT[kk][nl] = (n < N_) ? A[(size_t)n * DIN + k0 + kk] : 0.f;
    }
    for (int idx = tid; idx < 4096; idx += 256) {
      int kk = idx >> 6, cl = idx & 63;
      sW[kk][cl] = W[((size_t)r * DIN + k0 + kk) * HF + cg * 64 + cl];
    }
    __syncthreads();
#pragma unroll 8
    for (int kk = 0; kk < 64; ++kk) {
      const float4 a4 = *(const float4*)&sAT[kk][ty * 4];
      const float4 w4 = *(const float4*)&sW[kk][tx * 4];
      const float a[4] = {a4.x, a4.y, a4.z, a4.w};
      const float w[4] = {w4.x, w4.y, w4.z, w4.w};
#pragma unroll
      for (int i = 0; i < 4; ++i)
#pragma unroll
        for (int j = 0; j < 4; ++j) acc[i][j] = fmaf(a[i], w[j], acc[i][j]);
    }
    __syncthreads();
  }

  // store h (float4 per row)
  const int c0 = cg * 64 + tx * 4;
#pragma unroll
  for (int i = 0; i < 4; ++i) {
    int n = nb + ty * 4 + i;
    if (n < N_) {
      float4 v; v.x = acc[i][0]; v.y = acc[i][1]; v.z = acc[i][2]; v.w = acc[i][3];
      *(float4*)&h[((size_t)r * N_ + n) * HF + c0] = v;
    }
  }

  // fused el/er: reduce over f within head via shuffles (group width G = F/4)
  const int hh = c0 / F;
  const int f0 = c0 % F;
  float al4[4], ar4[4];
#pragma unroll
  for (int j = 0; j < 4; ++j) {
    al4[j] = al[((size_t)r * H + hh) * F + f0 + j];
    ar4[j] = ar[((size_t)r * H + hh) * F + f0 + j];
  }
  float elp[4], erp[4];
#pragma unroll
  for (int i = 0; i < 4; ++i) {
    elp[i] = acc[i][0] * al4[0] + acc[i][1] * al4[1] + acc[i][2] * al4[2] + acc[i][3] * al4[3];
    erp[i] = acc[i][0] * ar4[0] + acc[i][1] * ar4[1] + acc[i][2] * ar4[2] + acc[i][3] * ar4[3];
  }
  constexpr int G = F / 4;  // tx-threads per head: 16 (F=64) or 8 (F=32)
#pragma unroll
  for (int off = G / 2; off >= 1; off >>= 1) {
#pragma unroll
    for (int i = 0; i < 4; ++i) {
      elp[i] += __shfl_down(elp[i], off, G);
      erp[i] += __shfl_down(erp[i], off, G);
    }
  }
  if ((tx & (G - 1)) == 0) {
#pragma unroll
    for (int i = 0; i < 4; ++i) {
      int n = nb + ty * 4 + i;
      if (n < N_) {
        el[((size_t)r * N_ + n) * H + hh] = elp[i];
        er[((size_t)r * N_ + n) * H + hh] = erp[i];
      }
    }
  }
}

template <int DIN, int HF, int H, int F>
__global__ __launch_bounds__(256) void gemm_el_kernel(
    const float* __restrict__ A, const float* __restrict__ W,
    const float* __restrict__ al, const float* __restrict__ ar,
    float* __restrict__ h, float* __restrict__ el, float* __restrict__ er) {
  gemm_el_dev<DIN, HF, H, F>(blockIdx.z, A, W, al, ar, h, el, er);
}

// Batched variant: 3 instances (mu s0, mu s1, logvar), grid.z = 3*R_.
struct GemmB3 {
  const float* A[3]; const float* W[3]; const float* al[3]; const float* ar[3];
  float* h[3]; float* el[3]; float* er[3];
};
template <int DIN, int HF, int H, int F>
__global__ __launch_bounds__(256) void gemm_el_b3_kernel(GemmB3 a) {
  const int inst = blockIdx.z / R_;
  const int r    = blockIdx.z % R_;
  gemm_el_dev<DIN, HF, H, F>(r, a.A[inst], a.W[inst], a.al[inst], a.ar[inst],
                             a.h[inst], a.el[inst], a.er[inst]);
}

// ---------------- Per-destination edge softmax + aggregation ----------------
// One block per node; wave = head. Fast path (deg<=64 for all relations,
// which always holds at avg degree 10): all three relations' ptr/er/sp/el
// loads hoisted and issued together, butterflies interleaved 3-wide,
// gathers interleaved (raccv[3]). FP op sequence per relation and the
// cross-relation accumulation order are identical to the R5-verified code;
// deg==0 relations contribute exactly +0.0. Slow path = R5 loop verbatim.
template <int H, int F, bool RELU>
__device__ __forceinline__ void agg_dev(
    const int n, const float* __restrict__ h, const float* __restrict__ el,
    const float* __restrict__ er, const int* __restrict__ ptr,
    const int* __restrict__ srcs, const float* __restrict__ base,
    float* __restrict__ outf) {
  constexpr int VL  = F / 4;    // lanes per edge-row (float4 granules): 16 or 8
  constexpr int EPG = 64 / VL;  // edges per wave-iteration: 4 or 8
  const int wave = threadIdx.x >> 6;   // = head
  const int lane = threadIdx.x & 63;
  const int eg   = lane / VL;          // edge slot within iteration
  const int fl   = lane % VL;          // float4 index within row

  float4 tot = {0.f, 0.f, 0.f, 0.f};

  // hoisted ptr loads (independent across relations)
  int p0v[R_], degv[R_];
#pragma unroll
  for (int r = 0; r < R_; ++r) {
    p0v[r]  = ptr[r * (N_ + 1) + n];
    degv[r] = ptr[r * (N_ + 1) + n + 1] - p0v[r];
  }

  bool fast = true;
#pragma unroll
  for (int r = 0; r < R_; ++r) fast &= (degv[r] <= 64);

  if (__builtin_expect(fast, 1)) {
    // ---- fast path: single chunk per relation, fully pipelined ----
    float ervv[R_];
#pragma unroll
    for (int r = 0; r < R_; ++r)
      ervv[r] = er[((size_t)r * N_ + n) * H + wave];

    int sv[R_];
#pragma unroll
    for (int r = 0; r < R_; ++r)
      sv[r] = (lane < degv[r]) ? srcs[(size_t)r * E_ + p0v[r] + lane] : 0;

    float ev[R_];
#pragma unroll
    for (int r = 0; r < R_; ++r) {
      float e = -3.0e38f;
      if (lane < degv[r]) {
        e = el[((size_t)r * N_ + sv[r]) * H + wave] + ervv[r];
        e = (e > 0.f) ? e : 0.2f * e;
      }
      ev[r] = e;
    }

    // interleaved max butterflies (3 independent chains)
    float mv[R_];
#pragma unroll
    for (int r = 0; r < R_; ++r) mv[r] = ev[r];
#pragma unroll
    for (int off = 32; off >= 1; off >>= 1) {
#pragma unroll
      for (int r = 0; r < R_; ++r)
        mv[r] = fmaxf(mv[r], __shfl_xor(mv[r], off, 64));
    }

    // weights (exp(e - m); padded lanes -> exactly 0; deg==0 -> all 1 but
    // racc stays 0 so the relation contributes +0.0)
    float wv[R_];
#pragma unroll
    for (int r = 0; r < R_; ++r) wv[r] = __expf(ev[r] - mv[r]);

    // interleaved wsum butterflies
    float wsv[R_];
#pragma unroll
    for (int r = 0; r < R_; ++r) wsv[r] = wv[r];
#pragma unroll
    for (int off = 32; off >= 1; off >>= 1) {
#pragma unroll
      for (int r = 0; r < R_; ++r)
        wsv[r] += __shfl_xor(wsv[r], off, 64);
    }

    // interleaved gathers
    float4 raccv[R_];
#pragma unroll
    for (int r = 0; r < R_; ++r) raccv[r] = {0.f, 0.f, 0.f, 0.f};
    int kmaxv[R_];
#pragma unroll
    for (int r = 0; r < R_; ++r) kmaxv[r] = (degv[r] + EPG - 1) / EPG;
    int kmax_all = 0;
#pragma unroll
    for (int r = 0; r < R_; ++r) kmax_all = max(kmax_all, kmaxv[r]);

    for (int k = 0; k < kmax_all; ++k) {
      const int i2 = eg + k * EPG;  // < 64 always
#pragma unroll
      for (int r = 0; r < R_; ++r) {
        if (k < kmaxv[r]) {
          const int   s2 = __shfl(sv[r], i2, 64);
          const float w2 = __shfl(wv[r], i2, 64);
          const float4 hv =
              *(const float4*)&h[((size_t)r * N_ + s2) * (H * F) + wave * F + fl * 4];
          raccv[r].x = fmaf(w2, hv.x, raccv[r].x);
          raccv[r].y = fmaf(w2, hv.y, raccv[r].y);
          raccv[r].z = fmaf(w2, hv.z, raccv[r].z);
          raccv[r].w = fmaf(w2, hv.w, raccv[r].w);
        }
      }
    }

    // accumulate in relation order (identical to serial version)
#pragma unroll
    for (int r = 0; r < R_; ++r) {
      const float inv = 1.0f / (wsv[r] + 1e-16f);
      tot.x = fmaf(raccv[r].x, inv, tot.x);
      tot.y = fmaf(raccv[r].y, inv, tot.y);
      tot.z = fmaf(raccv[r].z, inv, tot.z);
      tot.w = fmaf(raccv[r].w, inv, tot.w);
    }
  } else {
    // ---- slow path: R5-verified chunked online softmax, verbatim ----
    for (int r = 0; r < R_; ++r) {
      const int p0  = p0v[r];
      const int deg = degv[r];
      if (deg == 0) continue;
      const int* sp = srcs + (size_t)r * E_ + p0;
      const float erv = er[((size_t)r * N_ + n) * H + wave];

      float m = -3.0e38f, dsum = 0.f;
      float4 racc = {0.f, 0.f, 0.f, 0.f};

      for (int b0 = 0; b0 < deg; b0 += 64) {
        const int cnt = min(64, deg - b0);
        int   s = 0;
        float e = -3.0e38f;
        if (lane < cnt) {
          s = sp[b0 + lane];
          e = el[((size_t)r * N_ + s) * H + wave] + erv;
          e = (e > 0.f) ? e : 0.2f * e;
        }
        float mloc = e;
#pragma unroll
        for (int off = 32; off >= 1; off >>= 1)
          mloc = fmaxf(mloc, __shfl_xor(mloc, off, 64));
        const float mnew  = fmaxf(m, mloc);
        const float scale = __expf(m - mnew);
        const float w = __expf(e - mnew);
        float wsum = w;
#pragma unroll
        for (int off = 32; off >= 1; off >>= 1)
          wsum += __shfl_xor(wsum, off, 64);
        dsum = fmaf(dsum, scale, wsum);
        racc.x *= scale; racc.y *= scale; racc.z *= scale; racc.w *= scale;
        m = mnew;

        const int kmax = (cnt + EPG - 1) / EPG;
        for (int k = 0; k < kmax; ++k) {
          const int i2 = eg + k * EPG;
          const int   s2 = __shfl(s, i2, 64);
          const float w2 = __shfl(w, i2, 64);
          const float4 hv =
              *(const float4*)&h[((size_t)r * N_ + s2) * (H * F) + wave * F + fl * 4];
          racc.x = fmaf(w2, hv.x, racc.x);
          racc.y = fmaf(w2, hv.y, racc.y);
          racc.z = fmaf(w2, hv.z, racc.z);
          racc.w = fmaf(w2, hv.w, racc.w);
        }
      }
      const float inv = 1.0f / (dsum + 1e-16f);
      tot.x = fmaf(racc.x, inv, tot.x);
      tot.y = fmaf(racc.y, inv, tot.y);
      tot.z = fmaf(racc.z, inv, tot.z);
      tot.w = fmaf(racc.w, inv, tot.w);
    }
  }

  // reduce across edge-groups (xor butterfly over offsets VL..32)
#pragma unroll
  for (int off = VL; off < 64; off <<= 1) {
    tot.x += __shfl_xor(tot.x, off, 64);
    tot.y += __shfl_xor(tot.y, off, 64);
    tot.z += __shfl_xor(tot.z, off, 64);
    tot.w += __shfl_xor(tot.w, off, 64);
  }

  __shared__ float4 sh4[H][VL];
  if (eg == 0) sh4[wave][fl] = tot;
  __syncthreads();
  if (threadIdx.x < VL) {
    float4 v = sh4[0][threadIdx.x];
#pragma unroll
    for (int hh = 1; hh < H; ++hh) {
      float4 u = sh4[hh][threadIdx.x];
      v.x += u.x; v.y += u.y; v.z += u.z; v.w += u.w;
    }
    const float sc = 1.0f / H;
    v.x *= sc; v.y *= sc; v.z *= sc; v.w *= sc;
    if (RELU) {
      v.x = fmaxf(v.x, 0.f); v.y = fmaxf(v.y, 0.f);
      v.z = fmaxf(v.z, 0.f); v.w = fmaxf(v.w, 0.f);
    }
    if (base) {
      float4 bv = *(const float4*)&base[(size_t)n * F + threadIdx.x * 4];
      v.x += bv.x; v.y += bv.y; v.z += bv.z; v.w += bv.w;
    }
    *(float4*)&outf[(size_t)n * F + threadIdx.x * 4] = v;
  }
}

template <int H, int F, bool RELU>
__global__ __launch_bounds__(256, 8) void agg_kernel(
    const float* __restrict__ h, const float* __restrict__ el, const float* __restrict__ er,
    const int* __restrict__ ptr, const int* __restrict__ srcs,
    const float* __restrict__ base, float* __restrict__ outf) {
  agg_dev<H, F, RELU>(blockIdx.x, h, el, er, ptr, srcs, base, outf);
}

// Batched agg: 3 instances (mu s0, mu s1, logvar), grid = (N, 3).
struct AggB3 {
  const float* h[3]; const float* el[3]; const float* er[3]; float* out[3];
};
__global__ __launch_bounds__(128, 8) void agg_b3_kernel(
    AggB3 a, const int* __restrict__ ptr, const int* __restrict__ srcs) {
  const int inst = blockIdx.y;
  agg_dev<2, 32, false>(blockIdx.x, a.h[inst], a.el[inst], a.er[inst],
                        ptr, srcs, nullptr, a.out[inst]);
}

// ---------------- adj = mean_s sigmoid(z1[s] @ z2[s]^T) ----------------
// R8: 256 threads, tile 128x128, 8x8 per thread with BOTH row and col quads
// split (rows ty*4 / 64+ty*4, cols tx*4 / 64+tx*4). All four fragment reads
// are contiguous float4 broadcast patterns (16 unique addrs, free). DS
// instructions per FMA halved vs the 8x4 version (4 per 64 vs 3 per 32).
// Per-element k-order and res accumulation identical -> bit-identical out.
__global__ __launch_bounds__(256) void adj_kernel(const float* __restrict__ mu,
                                                  float* __restrict__ out) {
  __shared__ float sA[32][128];  // [d][i_local]
  __shared__ float sB[32][128];  // [d][j_local]
  const int jb = blockIdx.x * 128;
  const int ib = blockIdx.y * 128;
  const int tid = threadIdx.x;
  const int ty = tid >> 4;   // 0..15: row quad base (rows ty*4 and 64+ty*4)
  const int tx = tid & 15;   // 0..15: col quad base (cols tx*4 and 64+tx*4)

  float res[8][8];
#pragma unroll
  for (int i = 0; i < 8; ++i)
#pragma unroll
    for (int j = 0; j < 8; ++j) res[i][j] = 0.f;

  for (int s = 0; s < 2; ++s) {
    __syncthreads();
#pragma unroll
    for (int it = 0; it < 4; ++it) {
      int idx = tid + it * 256;             // 0..1023
      int dg = idx >> 7, row = idx & 127;   // dg: 0..7 (float4 group of d)
      int gi = ib + row;
      int gj = jb + row;
      float4 va = {0.f, 0.f, 0.f, 0.f}, vb = {0.f, 0.f, 0.f, 0.f};
      if (gi < NB1) va = *(const float4*)&mu[((size_t)s * N_ + gi) * 32 + dg * 4];
      if (gj < NB1) vb = *(const float4*)&mu[((size_t)s * N_ + NB1 + gj) * 32 + dg * 4];
      sA[dg * 4 + 0][row] = va.x; sA[dg * 4 + 1][row] = va.y;
      sA[dg * 4 + 2][row] = va.z; sA[dg * 4 + 3][row] = va.w;
      sB[dg * 4 + 0][row] = vb.x; sB[dg * 4 + 1][row] = vb.y;
      sB[dg * 4 + 2][row] = vb.z; sB[dg * 4 + 3][row] = vb.w;
    }
    __syncthreads();

    float acc[8][8];
#pragma unroll
    for (int i = 0; i < 8; ++i)
#pragma unroll
      for (int j = 0; j < 8; ++j) acc[i][j] = 0.f;
#pragma unroll 8
    for (int k = 0; k < 32; ++k) {
      float a[8], b[8];
      *(float4*)&a[0] = *(const float4*)&sA[k][ty * 4];
      *(float4*)&a[4] = *(const float4*)&sA[k][64 + ty * 4];
      *(float4*)&b[0] = *(const float4*)&sB[k][tx * 4];
      *(float4*)&b[4] = *(const float4*)&sB[k][64 + tx * 4];
#pragma unroll
      for (int i = 0; i < 8; ++i)
#pragma unroll
        for (int j = 0; j < 8; ++j) acc[i][j] = fmaf(a[i], b[j], acc[i][j]);
    }
#pragma unroll
    for (int i = 0; i < 8; ++i)
#pragma unroll
      for (int j = 0; j < 8; ++j) res[i][j] += sigmoidf_(acc[i][j]);
  }

  const bool fullc = (jb + 128) <= NB1;
#pragma unroll
  for (int i = 0; i < 8; ++i) {
    int row = ib + ((i < 4) ? (ty * 4 + i) : (64 + ty * 4 + (i - 4)));
    if (row < NB1) {
      if (fullc) {
        float4 p0, p1;
        p0.x = 0.5f * res[i][0]; p0.y = 0.5f * res[i][1];
        p0.z = 0.5f * res[i][2]; p0.w = 0.5f * res[i][3];
        p1.x = 0.5f * res[i][4]; p1.y = 0.5f * res[i][5];
        p1.z = 0.5f * res[i][6]; p1.w = 0.5f * res[i][7];
        *(float4*)&out[(size_t)row * NB1 + jb + tx * 4]      = p0;
        *(float4*)&out[(size_t)row * NB1 + jb + 64 + tx * 4] = p1;
      } else {
#pragma unroll
        for (int j = 0; j < 8; ++j) {
          int col = jb + ((j < 4) ? (tx * 4 + j) : (64 + tx * 4 + (j - 4)));
          if (col < NB1) out[(size_t)row * NB1 + col] = 0.5f * res[i][j];
        }
      }
    }
  }
}

__global__ void rk2_kernel(const float* __restrict__ rk_lgt, float* __restrict__ out) {
  int i = threadIdx.x;
  if (i < 32) out[i] = sigmoidf_(rk_lgt[i]);
}

// ---------------- host ----------------
static inline size_t align256(size_t x) { return (x + 255) & ~(size_t)255; }

extern "C" void kernel_launch(void* const* d_in, const int* in_sizes, int n_in,
                              void* d_out, int out_size, void* d_ws, size_t ws_size,
                              hipStream_t stream) {
  (void)in_sizes; (void)n_in; (void)out_size; (void)d_ws; (void)ws_size;
  const float* x      = (const float*)d_in[0];
  const float* noise  = (const float*)d_in[1];
  const float* W1     = (const float*)d_in[2];
  const float* al1    = (const float*)d_in[3];
  const float* ar1    = (const float*)d_in[4];
  const float* We     = (const float*)d_in[5];
  const float* ale    = (const float*)d_in[6];
  const float* are    = (const float*)d_in[7];
  const float* W2     = (const float*)d_in[8];
  const float* al2    = (const float*)d_in[9];
  const float* ar2    = (const float*)d_in[10];
  const float* W3     = (const float*)d_in[11];
  const float* al3    = (const float*)d_in[12];
  const float* ar3    = (const float*)d_in[13];
  const float* rk_lgt = (const float*)d_in[14];
  const int*   src    = (const int*)d_in[15];
  const int*   dst    = (const int*)d_in[16];

  float* out_adj    = (float*)d_out;                       // (1,6000,6000)
  float* out_mu     = out_adj + (size_t)NB1 * NB1;         // (2,20000,32) @ 36,000,000
  float* out_logvar = out_mu + (size_t)2 * N_ * 32;        // (20000,32)   @ 37,280,000
  float* out_rk2    = out_logvar + (size_t)N_ * 32;        // (1,32)       @ 37,920,000

  // Scratch in the f32 adj region (144 MB; we use ~84.2 MB), dead before adj.
  char* sc = (char*)d_out;
  size_t off = 0;
  int*   ptr     = (int*)(sc + off);   off += align256((size_t)R_ * (N_ + 1) * 4);      //   240 KB
  int*   csums   = (int*)(sc + off);   off += align256((size_t)R_ * NCH * 4);           //     tiny
  int*   csr_src = (int*)(sc + off);   off += align256((size_t)R_ * E_ * 4);            //  2.40 MB
  float* el      = (float*)(sc + off); off += align256((size_t)R_ * N_ * 4 * 4);        //  0.96 MB
  float* er      = (float*)(sc + off); off += align256((size_t)R_ * N_ * 4 * 4);        //  0.96 MB
  float* el3     = (float*)(sc + off); off += align256((size_t)3 * R_ * N_ * 2 * 4);    //  1.44 MB
  float* er3     = (float*)(sc + off); off += align256((size_t)3 * R_ * N_ * 2 * 4);    //  1.44 MB
  float* hx      = (float*)(sc + off); off += align256((size_t)N_ * 64 * 4);            //  5.12 MB
  float* h1      = (float*)(sc + off); off += align256((size_t)2 * N_ * 64 * 4);        // 10.24 MB
  float* h       = (float*)(sc + off); off += align256((size_t)R_ * N_ * 256 * 4);      // 61.44 MB
  // total ~84.2 MB < 144 MB (f32 adj region)
  // counts/fill alias the h region (dead after CSR build; h written later)
  int* counts = (int*)(void*)h;
  int* fill   = (int*)(void*)((char*)(void*)h + align256((size_t)R_ * N_ * 4));
  // hM3 (3 x R x N x 64 f32 = 46.08 MB) aliases h (61.44 MB; h dead after
  // the last layer-1 agg). el3/er3 are DEDICATED (1.44 MB each; the R3/R4
  // bug was aliasing them onto the 0.96 MB el/er regions).
  float* hM3 = h;

  // ---- CSR (dst shared by all 6 rgat calls) ----
  hipMemsetAsync(counts, 0, (size_t)R_ * N_ * 4, stream);
  hipMemsetAsync(fill, 0, (size_t)R_ * N_ * 4, stream);
  int eblocks = (R_ * E_ + 255) / 256;
  hist_kernel<<<eblocks, 256, 0, stream>>>(dst, counts);
  scan_partial_kernel<<<dim3(NCH, R_), SCAN_CH, 0, stream>>>(counts, ptr, csums);
  scan_sums_kernel<<<1, 64, 0, stream>>>(csums, ptr);
  scan_add_kernel<<<dim3(NCH, R_), SCAN_CH, 0, stream>>>(csums, ptr);
  scatter_kernel<<<eblocks, 256, 0, stream>>>(src, dst, ptr, fill, csr_src);

  const dim3 g256((N_ + 63) / 64, 4, R_);

  // hiddenx = rgat(x, W1, al1, ar1, relu) -> hx (f32)
  gemm_el_kernel<128, 256, 4, 64><<<g256, 256, 0, stream>>>(x, W1, al1, ar1, h, el, er);
  agg_kernel<4, 64, true><<<N_, 256, 0, stream>>>(h, el, er, ptr, csr_src, nullptr, hx);

  // hidden1[s] = hiddenx + rgat(noise[s], We, ale, are, relu) -> h1 (f32)
  for (int s = 0; s < 2; ++s) {
    gemm_el_kernel<64, 256, 4, 64><<<g256, 256, 0, stream>>>(
        noise + (size_t)s * N_ * 64, We, ale, are, h, el, er);
    agg_kernel<4, 64, true><<<N_, 256, 0, stream>>>(
        h, el, er, ptr, csr_src, hx, h1 + (size_t)s * N_ * 64);
  }

  // Batched mu[s] (s=0,1) + logvar layers: one gemm dispatch, one agg dispatch.
  GemmB3 ga;
  AggB3  aa;
  const float* As[3]  = {h1, h1 + (size_t)N_ * 64, hx};
  const float* Ws[3]  = {W2, W2, W3};
  const float* als[3] = {al2, al2, al3};
  const float* ars[3] = {ar2, ar2, ar3};
  float* outs[3] = {out_mu, out_mu + (size_t)N_ * 32, out_logvar};
  for (int i = 0; i < 3; ++i) {
    ga.A[i]  = As[i];  ga.W[i]  = Ws[i]; ga.al[i] = als[i]; ga.ar[i] = ars[i];
    ga.h[i]  = hM3 + (size_t)i * R_ * N_ * 64;
    ga.el[i] = el3 + (size_t)i * R_ * N_ * 2;
    ga.er[i] = er3 + (size_t)i * R_ * N_ * 2;
    aa.h[i]  = ga.h[i];
    aa.el[i] = ga.el[i];
    aa.er[i] = ga.er[i];
    aa.out[i] = outs[i];
  }
  gemm_el_b3_kernel<64, 64, 2, 32><<<dim3((N_ + 63) / 64, 1, 3 * R_), 256, 0, stream>>>(ga);
  agg_b3_kernel<<<dim3(N_, 3), 128, 0, stream>>>(aa, ptr, csr_src);

  rk2_kernel<<<1, 32, 0, stream>>>(rk_lgt, out_rk2);

  // adj: reads out_mu (disjoint range), overwrites the adj-region scratch.
  adj_kernel<<<dim3((NB1 + 127) / 128, (NB1 + 127) / 128), 256, 0, stream>>>(out_mu, out_adj);
}

// Round 10
// 878.700 us; speedup vs baseline: 1.0809x; 1.0768x over previous
//
#include <hip/hip_runtime.h>
#include <hip/hip_bf16.h>

// RGAT pipeline for MI355X. Inputs f32, OUTPUTS f32. Scratch lives in d_out's
// f32 adj region (144 MB), all dead before adj_kernel. d_ws/d_in untouched.
//
// R1: agg flash-style online-softmax, vectorized multi-edge float4 gather.
// R2: adj 512-thr 8x4 blocking, conflict-free LDS.
// R3/R4 FAILED: el3/er3 under-allocation collided with er3[0]/hx.
// R5: dedicated el3/er3; 3-phase CSR scan; batched mu/mu/logvar layers.
// R6: agg software-pipelined across relations (fast path deg<=64 all r).
// R7/R8/R9: adj experiments. 8x8@256 FAILED the occupancy term: res[] in
//     AGPRs + 128 VGPR = ~256 unified regs/thread -> 2 waves/SIMD (Occ 19%),
//     DS latency unhidden, 108.9 us > 103. VALUBusy ~71us in ALL shapes ->
//     gfx94x-fallback counter overcounts; adj was never VALU-bound. REVERTED
//     to the measured-best 8x4@512 (102-103 us).
// R10: h stored in bf16 (the h-row gathers are the pipeline's dominant bytes:
//     318 MB FETCH per H=4 agg). Gather + gemm h-write bytes halve. Error
//     bound: |dh| <= |h|*2^-9; softmax-avg doesn't amplify; through layer-2
//     dmu ~ 0.004 RSS -> predicted absmax ~0.008-0.012 vs threshold 0.0195.
//     el/er/hx/h1/outputs all stay f32.

static constexpr int N_  = 20000;
static constexpr int R_  = 3;
static constexpr int E_  = 200000;
static constexpr int NB1 = 6000;   // N1 == N2 == 6000

__device__ __forceinline__ float sigmoidf_(float x) {
  return 1.0f / (1.0f + __expf(-x));
}

// f32 -> bf16 (RNE, finite inputs) and exact bf16 -> f32.
__device__ __forceinline__ unsigned short bf16_of_f32(float f) {
  unsigned int b = __float_as_uint(f);
  b += 0x7FFFu + ((b >> 16) & 1u);
  return (unsigned short)(b >> 16);
}
__device__ __forceinline__ float f32_of_bf16(unsigned short u) {
  return __uint_as_float((unsigned int)u << 16);
}

// ---------------- CSR build ----------------
__global__ void hist_kernel(const int* __restrict__ dst, int* __restrict__ counts) {
  int i = blockIdx.x * blockDim.x + threadIdx.x;
  if (i >= R_ * E_) return;
  int r = i / E_;
  atomicAdd(&counts[r * N_ + dst[i]], 1);
}

static constexpr int SCAN_CH = 1024;
static constexpr int NCH = (N_ + SCAN_CH - 1) / SCAN_CH;  // 20

// Phase A: per-1024-chunk local exclusive scan + chunk totals.
__global__ __launch_bounds__(1024) void scan_partial_kernel(
    const int* __restrict__ counts, int* __restrict__ ptr, int* __restrict__ csums) {
  const int r = blockIdx.y, c = blockIdx.x, tid = threadIdx.x;
  __shared__ int buf[SCAN_CH];
  const int i = c * SCAN_CH + tid;
  const int v = (i < N_) ? counts[r * N_ + i] : 0;
  buf[tid] = v;
  __syncthreads();
  for (int off = 1; off < SCAN_CH; off <<= 1) {
    int t = (tid >= off) ? buf[tid - off] : 0;
    __syncthreads();
    buf[tid] += t;
    __syncthreads();
  }
  if (i < N_) ptr[r * (N_ + 1) + i] = buf[tid] - v;  // local exclusive
  if (tid == SCAN_CH - 1) csums[r * NCH + c] = buf[tid];
}

// Phase B: tiny serial scan of chunk totals.
__global__ void scan_sums_kernel(int* __restrict__ csums, int* __restrict__ ptr) {
  int r = threadIdx.x;
  if (r < R_) {
    int acc = 0;
    for (int c = 0; c < NCH; ++c) {
      int t = csums[r * NCH + c];
      csums[r * NCH + c] = acc;
      acc += t;
    }
    ptr[r * (N_ + 1) + N_] = acc;
  }
}

// Phase C: add chunk bases.
__global__ __launch_bounds__(1024) void scan_add_kernel(
    const int* __restrict__ csums, int* __restrict__ ptr) {
  const int r = blockIdx.y, c = blockIdx.x, tid = threadIdx.x;
  const int i = c * SCAN_CH + tid;
  if (i < N_) ptr[r * (N_ + 1) + i] += csums[r * NCH + c];
}

__global__ void scatter_kernel(const int* __restrict__ src, const int* __restrict__ dst,
                               const int* __restrict__ ptr, int* __restrict__ fill,
                               int* __restrict__ csrc) {
  int i = blockIdx.x * blockDim.x + threadIdx.x;
  if (i >= R_ * E_) return;
  int r = i / E_;
  int d = dst[i];
  int pos = ptr[r * (N_ + 1) + d] + atomicAdd(&fill[r * N_ + d], 1);
  csrc[r * E_ + pos] = src[i];
}

// ---------------- GEMM + fused attention-logit epilogue ----------------
// h[r][n][HF] (bf16) = A[n][:] @ W[r][:][:]; el/er[r][n][hh] (f32) from the
// f32 accumulators. 256 threads = 16x16, tile 64x64, 4x4 register blocking.
template <int DIN, int HF, int H, int F>
__device__ __forceinline__ void gemm_el_dev(
    const int r, const float* __restrict__ A, const float* __restrict__ W,
    const float* __restrict__ al, const float* __restrict__ ar,
    unsigned short* __restrict__ h, float* __restrict__ el, float* __restrict__ er) {
  __shared__ float sAT[64][68];  // [k][node]
  __shared__ float sW[64][68];   // [k][col]
  const int nb  = blockIdx.x * 64;
  const int cg  = blockIdx.y;    // 64-col group
  const int tid = threadIdx.x;
  const int ty  = tid >> 4, tx = tid & 15;

  float acc[4][4];
#pragma unroll
  for (int i = 0; i < 4; ++i)
#pragma unroll
    for (int j = 0; j < 4; ++j) acc[i][j] = 0.f;

  for (int k0 = 0; k0 < DIN; k0 += 64) {
    for (int idx = tid; idx < 4096; idx += 256) {
      int nl = idx >> 6, kk = idx & 63;
      int n = nb + nl;
      sAT[kk][nl] = (n < N_) ? A[(size_t)n * DIN + k0 + kk] : 0.f;
    }
    for (int idx = tid; idx < 4096; idx += 256) {
      int kk = idx >> 6, cl = idx & 63;
      sW[kk][cl] = W[((size_t)r * DIN + k0 + kk) * HF + cg * 64 + cl];
    }
    __syncthreads();
#pragma unroll 8
    for (int kk = 0; kk < 64; ++kk) {
      const float4 a4 = *(const float4*)&sAT[kk][ty * 4];
      const float4 w4 = *(const float4*)&sW[kk][tx * 4];
      const float a[4] = {a4.x, a4.y, a4.z, a4.w};
      const float w[4] = {w4.x, w4.y, w4.z, w4.w};
#pragma unroll
      for (int i = 0; i < 4; ++i)
#pragma unroll
        for (int j = 0; j < 4; ++j) acc[i][j] = fmaf(a[i], w[j], acc[i][j]);
    }
    __syncthreads();
  }

  // store h as bf16 (ushort4 = 8B per row-quad)
  const int c0 = cg * 64 + tx * 4;
#pragma unroll
  for (int i = 0; i < 4; ++i) {
    int n = nb + ty * 4 + i;
    if (n < N_) {
      ushort4 v;
      v.x = bf16_of_f32(acc[i][0]); v.y = bf16_of_f32(acc[i][1]);
      v.z = bf16_of_f32(acc[i][2]); v.w = bf16_of_f32(acc[i][3]);
      *(ushort4*)&h[((size_t)r * N_ + n) * HF + c0] = v;
    }
  }

  // fused el/er from the full-precision f32 accumulators.
  const int hh = c0 / F;
  const int f0 = c0 % F;
  float al4[4], ar4[4];
#pragma unroll
  for (int j = 0; j < 4; ++j) {
    al4[j] = al[((size_t)r * H + hh) * F + f0 + j];
    ar4[j] = ar[((size_t)r * H + hh) * F + f0 + j];
  }
  float elp[4], erp[4];
#pragma unroll
  for (int i = 0; i < 4; ++i) {
    elp[i] = acc[i][0] * al4[0] + acc[i][1] * al4[1] + acc[i][2] * al4[2] + acc[i][3] * al4[3];
    erp[i] = acc[i][0] * ar4[0] + acc[i][1] * ar4[1] + acc[i][2] * ar4[2] + acc[i][3] * ar4[3];
  }
  constexpr int G = F / 4;  // tx-threads per head: 16 (F=64) or 8 (F=32)
#pragma unroll
  for (int off = G / 2; off >= 1; off >>= 1) {
#pragma unroll
    for (int i = 0; i < 4; ++i) {
      elp[i] += __shfl_down(elp[i], off, G);
      erp[i] += __shfl_down(erp[i], off, G);
    }
  }
  if ((tx & (G - 1)) == 0) {
#pragma unroll
    for (int i = 0; i < 4; ++i) {
      int n = nb + ty * 4 + i;
      if (n < N_) {
        el[((size_t)r * N_ + n) * H + hh] = elp[i];
        er[((size_t)r * N_ + n) * H + hh] = erp[i];
      }
    }
  }
}

template <int DIN, int HF, int H, int F>
__global__ __launch_bounds__(256) void gemm_el_kernel(
    const float* __restrict__ A, const float* __restrict__ W,
    const float* __restrict__ al, const float* __restrict__ ar,
    unsigned short* __restrict__ h, float* __restrict__ el, float* __restrict__ er) {
  gemm_el_dev<DIN, HF, H, F>(blockIdx.z, A, W, al, ar, h, el, er);
}

// Batched variant: 3 instances (mu s0, mu s1, logvar), grid.z = 3*R_.
struct GemmB3 {
  const float* A[3]; const float* W[3]; const float* al[3]; const float* ar[3];
  unsigned short* h[3]; float* el[3]; float* er[3];
};
template <int DIN, int HF, int H, int F>
__global__ __launch_bounds__(256) void gemm_el_b3_kernel(GemmB3 a) {
  const int inst = blockIdx.z / R_;
  const int r    = blockIdx.z % R_;
  gemm_el_dev<DIN, HF, H, F>(r, a.A[inst], a.W[inst], a.al[inst], a.ar[inst],
                             a.h[inst], a.el[inst], a.er[inst]);
}

// ---------------- Per-destination edge softmax + aggregation ----------------
// One block per node; wave = head. h is bf16 (ushort4 = 8B gather per lane,
// exact shift-convert to f32 before fmaf). Logits/weights/accums all f32.
template <int H, int F, bool RELU>
__device__ __forceinline__ void agg_dev(
    const int n, const unsigned short* __restrict__ h, const float* __restrict__ el,
    const float* __restrict__ er, const int* __restrict__ ptr,
    const int* __restrict__ srcs, const float* __restrict__ base,
    float* __restrict__ outf) {
  constexpr int VL  = F / 4;    // lanes per edge-row (4-elem granules): 16 or 8
  constexpr int EPG = 64 / VL;  // edges per wave-iteration: 4 or 8
  const int wave = threadIdx.x >> 6;   // = head
  const int lane = threadIdx.x & 63;
  const int eg   = lane / VL;          // edge slot within iteration
  const int fl   = lane % VL;          // 4-elem index within row

  float4 tot = {0.f, 0.f, 0.f, 0.f};

  // hoisted ptr loads (independent across relations)
  int p0v[R_], degv[R_];
#pragma unroll
  for (int r = 0; r < R_; ++r) {
    p0v[r]  = ptr[r * (N_ + 1) + n];
    degv[r] = ptr[r * (N_ + 1) + n + 1] - p0v[r];
  }

  bool fast = true;
#pragma unroll
  for (int r = 0; r < R_; ++r) fast &= (degv[r] <= 64);

  if (__builtin_expect(fast, 1)) {
    // ---- fast path: single chunk per relation, fully pipelined ----
    float ervv[R_];
#pragma unroll
    for (int r = 0; r < R_; ++r)
      ervv[r] = er[((size_t)r * N_ + n) * H + wave];

    int sv[R_];
#pragma unroll
    for (int r = 0; r < R_; ++r)
      sv[r] = (lane < degv[r]) ? srcs[(size_t)r * E_ + p0v[r] + lane] : 0;

    float ev[R_];
#pragma unroll
    for (int r = 0; r < R_; ++r) {
      float e = -3.0e38f;
      if (lane < degv[r]) {
        e = el[((size_t)r * N_ + sv[r]) * H + wave] + ervv[r];
        e = (e > 0.f) ? e : 0.2f * e;
      }
      ev[r] = e;
    }

    // interleaved max butterflies (3 independent chains)
    float mv[R_];
#pragma unroll
    for (int r = 0; r < R_; ++r) mv[r] = ev[r];
#pragma unroll
    for (int off = 32; off >= 1; off >>= 1) {
#pragma unroll
      for (int r = 0; r < R_; ++r)
        mv[r] = fmaxf(mv[r], __shfl_xor(mv[r], off, 64));
    }

    float wv[R_];
#pragma unroll
    for (int r = 0; r < R_; ++r) wv[r] = __expf(ev[r] - mv[r]);

    // interleaved wsum butterflies
    float wsv[R_];
#pragma unroll
    for (int r = 0; r < R_; ++r) wsv[r] = wv[r];
#pragma unroll
    for (int off = 32; off >= 1; off >>= 1) {
#pragma unroll
      for (int r = 0; r < R_; ++r)
        wsv[r] += __shfl_xor(wsv[r], off, 64);
    }

    // interleaved gathers (bf16 rows)
    float4 raccv[R_];
#pragma unroll
    for (int r = 0; r < R_; ++r) raccv[r] = {0.f, 0.f, 0.f, 0.f};
    int kmaxv[R_];
#pragma unroll
    for (int r = 0; r < R_; ++r) kmaxv[r] = (degv[r] + EPG - 1) / EPG;
    int kmax_all = 0;
#pragma unroll
    for (int r = 0; r < R_; ++r) kmax_all = max(kmax_all, kmaxv[r]);

    for (int k = 0; k < kmax_all; ++k) {
      const int i2 = eg + k * EPG;  // < 64 always
#pragma unroll
      for (int r = 0; r < R_; ++r) {
        if (k < kmaxv[r]) {
          const int   s2 = __shfl(sv[r], i2, 64);
          const float w2 = __shfl(wv[r], i2, 64);
          const ushort4 hv =
              *(const ushort4*)&h[((size_t)r * N_ + s2) * (H * F) + wave * F + fl * 4];
          raccv[r].x = fmaf(w2, f32_of_bf16(hv.x), raccv[r].x);
          raccv[r].y = fmaf(w2, f32_of_bf16(hv.y), raccv[r].y);
          raccv[r].z = fmaf(w2, f32_of_bf16(hv.z), raccv[r].z);
          raccv[r].w = fmaf(w2, f32_of_bf16(hv.w), raccv[r].w);
        }
      }
    }

    // accumulate in relation order (identical to serial version)
#pragma unroll
    for (int r = 0; r < R_; ++r) {
      const float inv = 1.0f / (wsv[r] + 1e-16f);
      tot.x = fmaf(raccv[r].x, inv, tot.x);
      tot.y = fmaf(raccv[r].y, inv, tot.y);
      tot.z = fmaf(raccv[r].z, inv, tot.z);
      tot.w = fmaf(raccv[r].w, inv, tot.w);
    }
  } else {
    // ---- slow path: R5-verified chunked online softmax ----
    for (int r = 0; r < R_; ++r) {
      const int p0  = p0v[r];
      const int deg = degv[r];
      if (deg == 0) continue;
      const int* sp = srcs + (size_t)r * E_ + p0;
      const float erv = er[((size_t)r * N_ + n) * H + wave];

      float m = -3.0e38f, dsum = 0.f;
      float4 racc = {0.f, 0.f, 0.f, 0.f};

      for (int b0 = 0; b0 < deg; b0 += 64) {
        const int cnt = min(64, deg - b0);
        int   s = 0;
        float e = -3.0e38f;
        if (lane < cnt) {
          s = sp[b0 + lane];
          e = el[((size_t)r * N_ + s) * H + wave] + erv;
          e = (e > 0.f) ? e : 0.2f * e;
        }
        float mloc = e;
#pragma unroll
        for (int off = 32; off >= 1; off >>= 1)
          mloc = fmaxf(mloc, __shfl_xor(mloc, off, 64));
        const float mnew  = fmaxf(m, mloc);
        const float scale = __expf(m - mnew);
        const float w = __expf(e - mnew);
        float wsum = w;
#pragma unroll
        for (int off = 32; off >= 1; off >>= 1)
          wsum += __shfl_xor(wsum, off, 64);
        dsum = fmaf(dsum, scale, wsum);
        racc.x *= scale; racc.y *= scale; racc.z *= scale; racc.w *= scale;
        m = mnew;

        const int kmax = (cnt + EPG - 1) / EPG;
        for (int k = 0; k < kmax; ++k) {
          const int i2 = eg + k * EPG;
          const int   s2 = __shfl(s, i2, 64);
          const float w2 = __shfl(w, i2, 64);
          const ushort4 hv =
              *(const ushort4*)&h[((size_t)r * N_ + s2) * (H * F) + wave * F + fl * 4];
          racc.x = fmaf(w2, f32_of_bf16(hv.x), racc.x);
          racc.y = fmaf(w2, f32_of_bf16(hv.y), racc.y);
          racc.z = fmaf(w2, f32_of_bf16(hv.z), racc.z);
          racc.w = fmaf(w2, f32_of_bf16(hv.w), racc.w);
        }
      }
      const float inv = 1.0f / (dsum + 1e-16f);
      tot.x = fmaf(racc.x, inv, tot.x);
      tot.y = fmaf(racc.y, inv, tot.y);
      tot.z = fmaf(racc.z, inv, tot.z);
      tot.w = fmaf(racc.w, inv, tot.w);
    }
  }

  // reduce across edge-groups (xor butterfly over offsets VL..32)
#pragma unroll
  for (int off = VL; off < 64; off <<= 1) {
    tot.x += __shfl_xor(tot.x, off, 64);
    tot.y += __shfl_xor(tot.y, off, 64);
    tot.z += __shfl_xor(tot.z, off, 64);
    tot.w += __shfl_xor(tot.w, off, 64);
  }

  __shared__ float4 sh4[H][VL];
  if (eg == 0) sh4[wave][fl] = tot;
  __syncthreads();
  if (threadIdx.x < VL) {
    float4 v = sh4[0][threadIdx.x];
#pragma unroll
    for (int hh = 1; hh < H; ++hh) {
      float4 u = sh4[hh][threadIdx.x];
      v.x += u.x; v.y += u.y; v.z += u.z; v.w += u.w;
    }
    const float sc = 1.0f / H;
    v.x *= sc; v.y *= sc; v.z *= sc; v.w *= sc;
    if (RELU) {
      v.x = fmaxf(v.x, 0.f); v.y = fmaxf(v.y, 0.f);
      v.z = fmaxf(v.z, 0.f); v.w = fmaxf(v.w, 0.f);
    }
    if (base) {
      float4 bv = *(const float4*)&base[(size_t)n * F + threadIdx.x * 4];
      v.x += bv.x; v.y += bv.y; v.z += bv.z; v.w += bv.w;
    }
    *(float4*)&outf[(size_t)n * F + threadIdx.x * 4] = v;
  }
}

template <int H, int F, bool RELU>
__global__ __launch_bounds__(256, 8) void agg_kernel(
    const unsigned short* __restrict__ h, const float* __restrict__ el,
    const float* __restrict__ er, const int* __restrict__ ptr,
    const int* __restrict__ srcs, const float* __restrict__ base,
    float* __restrict__ outf) {
  agg_dev<H, F, RELU>(blockIdx.x, h, el, er, ptr, srcs, base, outf);
}

// Batched agg: 3 instances (mu s0, mu s1, logvar), grid = (N, 3).
struct AggB3 {
  const unsigned short* h[3]; const float* el[3]; const float* er[3]; float* out[3];
};
__global__ __launch_bounds__(128, 8) void agg_b3_kernel(
    AggB3 a, const int* __restrict__ ptr, const int* __restrict__ srcs) {
  const int inst = blockIdx.y;
  agg_dev<2, 32, false>(blockIdx.x, a.h[inst], a.el[inst], a.er[inst],
                        ptr, srcs, nullptr, a.out[inst]);
}

// ---------------- adj = mean_s sigmoid(z1[s] @ z2[s]^T) ----------------
// Measured-best config (R2/R6: 102-103 us): 512 threads, tile 128x128, 8x4
// per thread. Conflict-free LDS staging and contiguous float4 fragment reads.
__global__ __launch_bounds__(512) void adj_kernel(const float* __restrict__ mu,
                                                  float* __restrict__ out) {
  __shared__ float sA[32][128];  // [d][i_local]
  __shared__ float sB[32][128];  // [d][j_local]
  const int jb = blockIdx.x * 128;
  const int ib = blockIdx.y * 128;
  const int tid = threadIdx.x;
  const int ty = tid >> 5;   // 0..15: row group (quad-split: ty*4 and 64+ty*4)
  const int tx = tid & 31;   // 0..31: col quad (tx*4)

  float res[8][4];
#pragma unroll
  for (int i = 0; i < 8; ++i)
#pragma unroll
    for (int j = 0; j < 4; ++j) res[i][j] = 0.f;

  for (int s = 0; s < 2; ++s) {
    __syncthreads();
#pragma unroll
    for (int it = 0; it < 2; ++it) {
      int idx = tid + it * 512;
      int dg = idx >> 7, row = idx & 127;   // dg: 0..7 (float4 group of d)
      int gi = ib + row;
      int gj = jb + row;
      float4 va = {0.f, 0.f, 0.f, 0.f}, vb = {0.f, 0.f, 0.f, 0.f};
      if (gi < NB1) va = *(const float4*)&mu[((size_t)s * N_ + gi) * 32 + dg * 4];
      if (gj < NB1) vb = *(const float4*)&mu[((size_t)s * N_ + NB1 + gj) * 32 + dg * 4];
      sA[dg * 4 + 0][row] = va.x; sA[dg * 4 + 1][row] = va.y;
      sA[dg * 4 + 2][row] = va.z; sA[dg * 4 + 3][row] = va.w;
      sB[dg * 4 + 0][row] = vb.x; sB[dg * 4 + 1][row] = vb.y;
      sB[dg * 4 + 2][row] = vb.z; sB[dg * 4 + 3][row] = vb.w;
    }
    __syncthreads();

    float acc[8][4];
#pragma unroll
    for (int i = 0; i < 8; ++i)
#pragma unroll
      for (int j = 0; j < 4; ++j) acc[i][j] = 0.f;
#pragma unroll 8
    for (int k = 0; k < 32; ++k) {
      float a[8], b[4];
      *(float4*)&a[0] = *(const float4*)&sA[k][ty * 4];
      *(float4*)&a[4] = *(const float4*)&sA[k][64 + ty * 4];
      *(float4*)&b[0] = *(const float4*)&sB[k][tx * 4];
#pragma unroll
      for (int i = 0; i < 8; ++i)
#pragma unroll
        for (int j = 0; j < 4; ++j) acc[i][j] = fmaf(a[i], b[j], acc[i][j]);
    }
#pragma unroll
    for (int i = 0; i < 8; ++i)
#pragma unroll
      for (int j = 0; j < 4; ++j) res[i][j] += sigmoidf_(acc[i][j]);
  }

  const bool fullc = (jb + 128) <= NB1;
#pragma unroll
  for (int i = 0; i < 8; ++i) {
    int row = ib + ((i < 4) ? (ty * 4 + i) : (64 + ty * 4 + (i - 4)));
    if (row < NB1) {
      int col = jb + tx * 4;
      if (fullc) {
        float4 p;
        p.x = 0.5f * res[i][0]; p.y = 0.5f * res[i][1];
        p.z = 0.5f * res[i][2]; p.w = 0.5f * res[i][3];
        *(float4*)&out[(size_t)row * NB1 + col] = p;
      } else {
#pragma unroll
        for (int j = 0; j < 4; ++j) {
          if (col + j < NB1) out[(size_t)row * NB1 + col + j] = 0.5f * res[i][j];
        }
      }
    }
  }
}

__global__ void rk2_kernel(const float* __restrict__ rk_lgt, float* __restrict__ out) {
  int i = threadIdx.x;
  if (i < 32) out[i] = sigmoidf_(rk_lgt[i]);
}

// ---------------- host ----------------
static inline size_t align256(size_t x) { return (x + 255) & ~(size_t)255; }

extern "C" void kernel_launch(void* const* d_in, const int* in_sizes, int n_in,
                              void* d_out, int out_size, void* d_ws, size_t ws_size,
                              hipStream_t stream) {
  (void)in_sizes; (void)n_in; (void)out_size; (void)d_ws; (void)ws_size;
  const float* x      = (const float*)d_in[0];
  const float* noise  = (const float*)d_in[1];
  const float* W1     = (const float*)d_in[2];
  const float* al1    = (const float*)d_in[3];
  const float* ar1    = (const float*)d_in[4];
  const float* We     = (const float*)d_in[5];
  const float* ale    = (const float*)d_in[6];
  const float* are    = (const float*)d_in[7];
  const float* W2     = (const float*)d_in[8];
  const float* al2    = (const float*)d_in[9];
  const float* ar2    = (const float*)d_in[10];
  const float* W3     = (const float*)d_in[11];
  const float* al3    = (const float*)d_in[12];
  const float* ar3    = (const float*)d_in[13];
  const float* rk_lgt = (const float*)d_in[14];
  const int*   src    = (const int*)d_in[15];
  const int*   dst    = (const int*)d_in[16];

  float* out_adj    = (float*)d_out;                       // (1,6000,6000)
  float* out_mu     = out_adj + (size_t)NB1 * NB1;         // (2,20000,32) @ 36,000,000
  float* out_logvar = out_mu + (size_t)2 * N_ * 32;        // (20000,32)   @ 37,280,000
  float* out_rk2    = out_logvar + (size_t)N_ * 32;        // (1,32)       @ 37,920,000

  // Scratch in the f32 adj region (144 MB), dead before adj.
  char* sc = (char*)d_out;
  size_t off = 0;
  int*   ptr     = (int*)(sc + off);   off += align256((size_t)R_ * (N_ + 1) * 4);      //   240 KB
  int*   csums   = (int*)(sc + off);   off += align256((size_t)R_ * NCH * 4);           //     tiny
  int*   csr_src = (int*)(sc + off);   off += align256((size_t)R_ * E_ * 4);            //  2.40 MB
  float* el      = (float*)(sc + off); off += align256((size_t)R_ * N_ * 4 * 4);        //  0.96 MB
  float* er      = (float*)(sc + off); off += align256((size_t)R_ * N_ * 4 * 4);        //  0.96 MB
  float* el3     = (float*)(sc + off); off += align256((size_t)3 * R_ * N_ * 2 * 4);    //  1.44 MB
  float* er3     = (float*)(sc + off); off += align256((size_t)3 * R_ * N_ * 2 * 4);    //  1.44 MB
  float* hx      = (float*)(sc + off); off += align256((size_t)N_ * 64 * 4);            //  5.12 MB
  float* h1      = (float*)(sc + off); off += align256((size_t)2 * N_ * 64 * 4);        // 10.24 MB
  unsigned short* h = (unsigned short*)(sc + off);
  off += align256((size_t)R_ * N_ * 256 * 2);                                           // 30.72 MB
  // total ~53.5 MB < 144 MB (f32 adj region)
  // counts/fill alias the h region (dead after CSR build; h written later)
  int* counts = (int*)(void*)h;
  int* fill   = (int*)(void*)((char*)(void*)h + align256((size_t)R_ * N_ * 4));
  // hM3 (3 x R x N x 64 bf16 = 23.04 MB) aliases h (30.72 MB; h dead after
  // the last layer-1 agg). el3/er3 are DEDICATED (R3/R4 aliasing bug).
  unsigned short* hM3 = h;

  // ---- CSR (dst shared by all 6 rgat calls) ----
  hipMemsetAsync(counts, 0, (size_t)R_ * N_ * 4, stream);
  hipMemsetAsync(fill, 0, (size_t)R_ * N_ * 4, stream);
  int eblocks = (R_ * E_ + 255) / 256;
  hist_kernel<<<eblocks, 256, 0, stream>>>(dst, counts);
  scan_partial_kernel<<<dim3(NCH, R_), SCAN_CH, 0, stream>>>(counts, ptr, csums);
  scan_sums_kernel<<<1, 64, 0, stream>>>(csums, ptr);
  scan_add_kernel<<<dim3(NCH, R_), SCAN_CH, 0, stream>>>(csums, ptr);
  scatter_kernel<<<eblocks, 256, 0, stream>>>(src, dst, ptr, fill, csr_src);

  const dim3 g256((N_ + 63) / 64, 4, R_);

  // hiddenx = rgat(x, W1, al1, ar1, relu) -> hx (f32)
  gemm_el_kernel<128, 256, 4, 64><<<g256, 256, 0, stream>>>(x, W1, al1, ar1, h, el, er);
  agg_kernel<4, 64, true><<<N_, 256, 0, stream>>>(h, el, er, ptr, csr_src, nullptr, hx);

  // hidden1[s] = hiddenx + rgat(noise[s], We, ale, are, relu) -> h1 (f32)
  for (int s = 0; s < 2; ++s) {
    gemm_el_kernel<64, 256, 4, 64><<<g256, 256, 0, stream>>>(
        noise + (size_t)s * N_ * 64, We, ale, are, h, el, er);
    agg_kernel<4, 64, true><<<N_, 256, 0, stream>>>(
        h, el, er, ptr, csr_src, hx, h1 + (size_t)s * N_ * 64);
  }

  // Batched mu[s] (s=0,1) + logvar layers: one gemm dispatch, one agg dispatch.
  GemmB3 ga;
  AggB3  aa;
  const float* As[3]  = {h1, h1 + (size_t)N_ * 64, hx};
  const float* Ws[3]  = {W2, W2, W3};
  const float* als[3] = {al2, al2, al3};
  const float* ars[3] = {ar2, ar2, ar3};
  float* outs[3] = {out_mu, out_mu + (size_t)N_ * 32, out_logvar};
  for (int i = 0; i < 3; ++i) {
    ga.A[i]  = As[i];  ga.W[i]  = Ws[i]; ga.al[i] = als[i]; ga.ar[i] = ars[i];
    ga.h[i]  = hM3 + (size_t)i * R_ * N_ * 64;
    ga.el[i] = el3 + (size_t)i * R_ * N_ * 2;
    ga.er[i] = er3 + (size_t)i * R_ * N_ * 2;
    aa.h[i]  = ga.h[i];
    aa.el[i] = ga.el[i];
    aa.er[i] = ga.er[i];
    aa.out[i] = outs[i];
  }
  gemm_el_b3_kernel<64, 64, 2, 32><<<dim3((N_ + 63) / 64, 1, 3 * R_), 256, 0, stream>>>(ga);
  agg_b3_kernel<<<dim3(N_, 3), 128, 0, stream>>>(aa, ptr, csr_src);

  rk2_kernel<<<1, 32, 0, stream>>>(rk_lgt, out_rk2);

  // adj: reads out_mu (disjoint range), overwrites the adj-region scratch.
  adj_kernel<<<dim3((NB1 + 127) / 128, (NB1 + 127) / 128), 512, 0, stream>>>(out_mu, out_adj);
}